// Round 1
// baseline (119.589 us; speedup 1.0000x reference)
//
#include <hip/hip_runtime.h>
#include <hip/hip_bf16.h>

// EasyExprGNN: B=8, S=4096, N=32, H=32, D=64, O=32. T = B*S = 32768 tokens.
//
// Folded formulation (exact algebra):
//   per (token, n): centered = nb*a + ei*c + d  (a,c,d = mean-centered nW1 rows / nb1)
//                   var = quadratic(nb, ei) via 6 scalars; inv = rsqrt(var+eps)
//                   r_j = relu((nb*Ag_j + ei*Cg_j + Dg_j)*inv + nlb_j);  nsum_j = sum_n r_j
//   self: e_j = relu((ex*Asg_j + Dsg_j)*inv_s + slb_j)
//   y_m = sum_k e_k*G[k][m] + sum_k nsum_k*G[32+k][m] + cvec[m]   (G = branchW2 (x) hW1 fused)
//   out_j = relu(LN64(y)*hlg+hlb) @ hW2 + hb2; masked -> 0

#define LN_EPS 1e-5f

// ---------------- fold kernel: precompute folded weights into ws ----------------
// ws float layout:
//   [0,32) Ag  [32,64) Cg  [64,96) Dg  [96,128) nlb
//   [128,134) qaa,qcc,qdd,qac,qad,qcd
//   [134,166) Asg [166,198) Dsg [198,230) slb  [230,233) saa,sad,sdd
//   [256,4352) G[64][64] (k-major; k<32 = self channels via sW2, k>=32 = nsum via nW2)
//   [4352,4416) cvec[64]
__global__ __launch_bounds__(256) void gnn_fold(
    const float* __restrict__ nW1, const float* __restrict__ nb1,
    const float* __restrict__ nlg, const float* __restrict__ nlb,
    const float* __restrict__ nW2, const float* __restrict__ nb2,
    const float* __restrict__ sW1, const float* __restrict__ sb1,
    const float* __restrict__ slg, const float* __restrict__ slb,
    const float* __restrict__ sW2, const float* __restrict__ sb2,
    const float* __restrict__ hW1, const float* __restrict__ hb1,
    float* __restrict__ ws)
{
    int tid = blockIdx.x * 256 + threadIdx.x;   // 0..4095 -> one G entry each
    int k = tid >> 6, m = tid & 63;
    float acc = 0.f;
    if (k < 32) {
        #pragma unroll 8
        for (int i = 0; i < 32; ++i) acc = fmaf(sW2[k*32 + i], hW1[i*64 + m], acc);
    } else {
        int kk = k - 32;
        #pragma unroll 8
        for (int i = 0; i < 32; ++i) acc = fmaf(nW2[kk*32 + i], hW1[(32 + i)*64 + m], acc);
    }
    ws[256 + k*64 + m] = acc;

    if (blockIdx.x == 0) {
        int t = threadIdx.x;
        if (t < 64) {
            // cvec[m] = hb1[m] + sb2 @ hW1_top[:,m] + 32 * nb2 @ hW1_bot[:,m]
            float c = hb1[t];
            for (int i = 0; i < 32; ++i) {
                c = fmaf(sb2[i], hW1[i*64 + t], c);
                c = fmaf(32.f * nb2[i], hW1[(32 + i)*64 + t], c);
            }
            ws[4352 + t] = c;
        } else if (t < 96) {
            int j = t - 64;
            float m0 = 0.f, m1 = 0.f, mb = 0.f;
            for (int i = 0; i < 32; ++i) { m0 += nW1[i]; m1 += nW1[32 + i]; mb += nb1[i]; }
            m0 *= (1.f/32.f); m1 *= (1.f/32.f); mb *= (1.f/32.f);
            float a = nW1[j] - m0, c = nW1[32 + j] - m1, d = nb1[j] - mb;
            ws[j]       = a * nlg[j];
            ws[32 + j]  = c * nlg[j];
            ws[64 + j]  = d * nlg[j];
            ws[96 + j]  = nlb[j];
            float ms = 0.f, msb = 0.f;
            for (int i = 0; i < 32; ++i) { ms += sW1[i]; msb += sb1[i]; }
            ms *= (1.f/32.f); msb *= (1.f/32.f);
            float as = sW1[j] - ms, ds = sb1[j] - msb;
            ws[134 + j] = as * slg[j];
            ws[166 + j] = ds * slg[j];
            ws[198 + j] = slb[j];
        } else if (t == 96) {
            float m0 = 0.f, m1 = 0.f, mb = 0.f;
            for (int i = 0; i < 32; ++i) { m0 += nW1[i]; m1 += nW1[32 + i]; mb += nb1[i]; }
            m0 *= (1.f/32.f); m1 *= (1.f/32.f); mb *= (1.f/32.f);
            float qaa=0,qcc=0,qdd=0,qac=0,qad=0,qcd=0;
            for (int j = 0; j < 32; ++j) {
                float a = nW1[j] - m0, c = nW1[32 + j] - m1, d = nb1[j] - mb;
                qaa += a*a; qcc += c*c; qdd += d*d; qac += a*c; qad += a*d; qcd += c*d;
            }
            ws[128]=qaa*(1.f/32.f); ws[129]=qcc*(1.f/32.f); ws[130]=qdd*(1.f/32.f);
            ws[131]=qac*(1.f/32.f); ws[132]=qad*(1.f/32.f); ws[133]=qcd*(1.f/32.f);
            float ms = 0.f, msb = 0.f;
            for (int i = 0; i < 32; ++i) { ms += sW1[i]; msb += sb1[i]; }
            ms *= (1.f/32.f); msb *= (1.f/32.f);
            float saa=0, sad=0, sdd=0;
            for (int j = 0; j < 32; ++j) {
                float as = sW1[j] - ms, ds = sb1[j] - msb;
                saa += as*as; sad += as*ds; sdd += ds*ds;
            }
            ws[230]=saa*(1.f/32.f); ws[231]=sad*(1.f/32.f); ws[232]=sdd*(1.f/32.f);
        }
    }
}

// ---------------- main kernel: 64 tokens per block of 256 threads ----------------
__global__ __launch_bounds__(256) void gnn_main(
    const float* __restrict__ expr, const float* __restrict__ neighbors,
    const float* __restrict__ edge_info, const int* __restrict__ mask,
    const float* __restrict__ hlg, const float* __restrict__ hlb,
    const float* __restrict__ hW2, const float* __restrict__ hb2,
    const float* __restrict__ ws, float* __restrict__ out)
{
    __shared__ float s_feat[64 * 33 * 2];   // (tok*33+n)*2 + {0:nb, 1:ei}; odd stride -> no conflicts
    __shared__ float s_inv[64 * 33];        // tok*33 + n
    __shared__ float s_X[64 * 65];          // tok*65 + k  (phase B input X, reused for Y')
    __shared__ float s_red[64 * 9];         // tok*9 + w*2 + {0,1}  LN partials
    __shared__ float s_expr[64];

    const int t  = threadIdx.x;
    const int g0 = blockIdx.x * 64;         // first global token of this block
    const int bb = g0 >> 12;                // batch (S=4096 divides 64 evenly -> no crossing)
    const int s0 = g0 & 4095;
    const float* nbp = neighbors + ((size_t)bb * 32 * 4096 + s0);
    const float* eip = edge_info + (size_t)g0 * 32;

    // ---- stage neighbors (transposing) + edge_info into interleaved feat ----
    #pragma unroll
    for (int i = 0; i < 8; ++i) {
        int idx = i * 256 + t;
        int n = idx >> 6, col = idx & 63;   // coalesced 256B reads per wave
        s_feat[(col * 33 + n) * 2 + 0] = nbp[n * 4096 + col];
    }
    #pragma unroll
    for (int i = 0; i < 8; ++i) {
        int idx = i * 256 + t;
        int tok = idx >> 5, n = idx & 31;
        s_feat[(tok * 33 + n) * 2 + 1] = eip[idx];
    }
    if (t < 64) s_expr[t] = expr[g0 + t];
    __syncthreads();

    // ---- inv pass: rsqrt of the LN variance quadratic, per (token, n) ----
    {
        float qaa = ws[128], qcc = ws[129], qdd = ws[130];
        float qac = ws[131], qad = ws[132], qcd = ws[133];
        #pragma unroll
        for (int i = 0; i < 8; ++i) {
            int idx = i * 256 + t;
            int tok = idx >> 5, n = idx & 31;
            float2 f = *(const float2*)&s_feat[(tok * 33 + n) * 2];
            float nb = f.x, ei = f.y;
            float v = qdd + nb * (qaa * nb + 2.f * qad) + ei * (qcc * ei + 2.f * qcd)
                    + 2.f * qac * nb * ei;
            s_inv[tok * 33 + n] = rsqrtf(v + LN_EPS);
        }
    }
    __syncthreads();

    // ---- phase A: neighbor accumulation. 4 threads/token, 8 channels each ----
    const int tok = t >> 2;
    const int jb  = (t & 3) * 8;
    float Ag[8], Cg[8], Dg[8], lbv[8];
    #pragma unroll
    for (int i = 0; i < 8; ++i) {
        Ag[i]  = ws[jb + i];
        Cg[i]  = ws[32 + jb + i];
        Dg[i]  = ws[64 + jb + i];
        lbv[i] = ws[96 + jb + i];
    }
    float nsum[8] = {0,0,0,0,0,0,0,0};
    #pragma unroll 4
    for (int n = 0; n < 32; ++n) {
        float2 f  = *(const float2*)&s_feat[(tok * 33 + n) * 2];
        float inv = s_inv[tok * 33 + n];
        #pragma unroll
        for (int i = 0; i < 8; ++i) {
            float r = fmaf(f.x, Ag[i], Dg[i]);
            r = fmaf(f.y, Cg[i], r);
            r = fmaf(r, inv, lbv[i]);
            nsum[i] += fmaxf(r, 0.f);
        }
    }

    // ---- self branch + write X = [e | nsum] ----
    {
        float ex  = s_expr[tok];
        float saa = ws[230], sad = ws[231], sdd = ws[232];
        float vs  = fmaf(ex, fmaf(ex, saa, 2.f * sad), sdd);
        float invs = rsqrtf(vs + LN_EPS);
        #pragma unroll
        for (int i = 0; i < 8; ++i) {
            float r = fmaf(ex, ws[134 + jb + i], ws[166 + jb + i]);
            r = fmaf(r, invs, ws[198 + jb + i]);
            s_X[tok * 65 + jb + i]      = fmaxf(r, 0.f);
            s_X[tok * 65 + 32 + jb + i] = nsum[i];
        }
    }
    __syncthreads();

    // ---- phase B: y = X @ G + cvec. wave w owns channels [16w,16w+16), lane = token ----
    const int w = __builtin_amdgcn_readfirstlane(t >> 6);  // wave-uniform -> s_load weights
    const int l = t & 63;
    const float* Gp = ws + 256 + w * 16;
    const float* cv = ws + 4352 + w * 16;
    float y[16];
    #pragma unroll
    for (int i = 0; i < 16; ++i) y[i] = cv[i];
    #pragma unroll 4
    for (int k = 0; k < 64; ++k) {
        float xk = s_X[l * 65 + k];
        const float* gk = Gp + k * 64;
        #pragma unroll
        for (int i = 0; i < 16; ++i) y[i] = fmaf(xk, gk[i], y[i]);
    }

    // ---- LN over 64 channels (split across 4 waves) ----
    float sm = 0.f, s2 = 0.f;
    #pragma unroll
    for (int i = 0; i < 16; ++i) { sm += y[i]; s2 = fmaf(y[i], y[i], s2); }
    s_red[l * 9 + w * 2 + 0] = sm;
    s_red[l * 9 + w * 2 + 1] = s2;
    __syncthreads();          // also guarantees all phase-B reads of s_X are done
    float tot = 0.f, tot2 = 0.f;
    #pragma unroll
    for (int r = 0; r < 4; ++r) {
        tot  += s_red[l * 9 + r * 2 + 0];
        tot2 += s_red[l * 9 + r * 2 + 1];
    }
    float mean = tot * (1.f / 64.f);
    float var  = tot2 * (1.f / 64.f) - mean * mean;
    float linv = rsqrtf(var + LN_EPS);
    #pragma unroll
    for (int i = 0; i < 16; ++i) {
        float v = (y[i] - mean) * linv;
        v = fmaf(v, hlg[w * 16 + i], hlb[w * 16 + i]);
        y[i] = fmaxf(v, 0.f);
    }
    #pragma unroll
    for (int i = 0; i < 16; ++i) s_X[l * 65 + w * 16 + i] = y[i];  // reuse s_X for Y'
    __syncthreads();

    // ---- phase C: out = Y' @ hW2 + hb2. wave w owns out channels [8w, 8w+8) ----
    const int ob = w * 8;
    float o[8];
    #pragma unroll
    for (int i = 0; i < 8; ++i) o[i] = hb2[ob + i];
    #pragma unroll 4
    for (int m = 0; m < 64; ++m) {
        float ym = s_X[l * 65 + m];
        const float* h2 = hW2 + m * 32 + ob;
        #pragma unroll
        for (int i = 0; i < 8; ++i) o[i] = fmaf(ym, h2[i], o[i]);
    }
    int mk = mask[g0 + l];
    float4 o0 = make_float4(o[0], o[1], o[2], o[3]);
    float4 o1 = make_float4(o[4], o[5], o[6], o[7]);
    if (mk) { o0 = make_float4(0.f,0.f,0.f,0.f); o1 = o0; }
    float4* op = (float4*)(out + (size_t)(g0 + l) * 32 + ob);
    op[0] = o0;
    op[1] = o1;
}

extern "C" void kernel_launch(void* const* d_in, const int* in_sizes, int n_in,
                              void* d_out, int out_size, void* d_ws, size_t ws_size,
                              hipStream_t stream) {
    const float* expr      = (const float*)d_in[0];
    const float* neighbors = (const float*)d_in[1];
    const float* edge_info = (const float*)d_in[2];
    const int*   mask      = (const int*)d_in[3];
    const float* nW1 = (const float*)d_in[4];
    const float* nb1 = (const float*)d_in[5];
    const float* nlg = (const float*)d_in[6];
    const float* nlb = (const float*)d_in[7];
    const float* nW2 = (const float*)d_in[8];
    const float* nb2 = (const float*)d_in[9];
    const float* sW1 = (const float*)d_in[10];
    const float* sb1 = (const float*)d_in[11];
    const float* slg = (const float*)d_in[12];
    const float* slb = (const float*)d_in[13];
    const float* sW2 = (const float*)d_in[14];
    const float* sb2 = (const float*)d_in[15];
    const float* hW1 = (const float*)d_in[16];
    const float* hb1 = (const float*)d_in[17];
    const float* hlg = (const float*)d_in[18];
    const float* hlb = (const float*)d_in[19];
    const float* hW2 = (const float*)d_in[20];
    const float* hb2 = (const float*)d_in[21];
    float* ws  = (float*)d_ws;
    float* out = (float*)d_out;

    gnn_fold<<<16, 256, 0, stream>>>(nW1, nb1, nlg, nlb, nW2, nb2,
                                     sW1, sb1, slg, slb, sW2, sb2,
                                     hW1, hb1, ws);
    gnn_main<<<512, 256, 0, stream>>>(expr, neighbors, edge_info, mask,
                                      hlg, hlb, hW2, hb2, ws, out);
}